// Round 22
// baseline (170.982 us; speedup 1.0000x reference)
//
#include <hip/hip_runtime.h>
#include <hip/hip_bf16.h>
#include <stdint.h>

typedef unsigned short u16;
typedef unsigned int u32;

#define D_MODEL 1024
#define NHEADS 16
#define DK 64
#define BB 4
#define SS 2048
#define M_TOT (BB * SS)  // 8192
#define QK_SCALE 0.18033688011112042f  // 0.125 * log2(e)

typedef __attribute__((ext_vector_type(8))) short short8;
typedef __attribute__((ext_vector_type(8))) __bf16 bf16x8;
typedef __attribute__((ext_vector_type(4))) float f32x4;

static __device__ __forceinline__ f32x4 mfma16(short8 a, short8 b, f32x4 c) {
  return __builtin_amdgcn_mfma_f32_16x16x32_bf16(
      __builtin_bit_cast(bf16x8, a), __builtin_bit_cast(bf16x8, b), c, 0, 0, 0);
}

// round-to-nearest-even f32 -> bf16
static __device__ __forceinline__ u16 f2bf(float f) {
  u32 u = __builtin_bit_cast(u32, f);
  u += 0x7fffu + ((u >> 16) & 1u);
  return (u16)(u >> 16);
}

// packed f32x2 -> bf16x2 (RNE); dst.lo = lo, dst.hi = hi
static __device__ __forceinline__ u32 cvtpk(float lo, float hi) {
  u32 r;
  asm("v_cvt_pk_bf16_f32 %0, %1, %2" : "=v"(r) : "v"(lo), "v"(hi));
  return r;
}
// swap a.lanes[32:63] <-> b.lanes[0:31]   (vdst.hi32 <-> vsrc.lo32)
static __device__ __forceinline__ void pl32swap(u32& a, u32& b) {
  asm("v_permlane32_swap_b32 %0, %1" : "+v"(a), "+v"(b));
}
// swap a.odd-16-rows <-> b.even-16-rows
static __device__ __forceinline__ void pl16swap(u32& a, u32& b) {
  asm("v_permlane16_swap_b32 %0, %1" : "+v"(a), "+v"(b));
}

// counted waits (attn / gemm_out only)
#define WAITV4 asm volatile("s_waitcnt vmcnt(4)" ::: "memory")
#define WAITV0 asm volatile("s_waitcnt vmcnt(0)" ::: "memory")
#define WAITLGKM0 asm volatile("s_waitcnt lgkmcnt(0)" ::: "memory")

// ---------------- f32 -> bf16 convert (Wo only) ----------------
__global__ void cvt1_kernel(const float* __restrict__ s0, u16* __restrict__ d0, int n4) {
  int stride = gridDim.x * blockDim.x;
  for (int i = blockIdx.x * blockDim.x + threadIdx.x; i < n4; i += stride) {
    float4 v = reinterpret_cast<const float4*>(s0)[i];
    ushort4 o;
    o.x = f2bf(v.x); o.y = f2bf(v.y); o.z = f2bf(v.z); o.w = f2bf(v.w);
    reinterpret_cast<ushort4*>(d0)[i] = o;
  }
}

// ---------- mask prefix scan: inv[b][i] = i-th valid kv pos; Sv[b] --------
__global__ void scan_kernel(const int* __restrict__ mask, int* __restrict__ inv,
                            int* __restrict__ Sv) {
  __shared__ int part[256];
  const int b = blockIdx.x, tid = threadIdx.x;
  const int* m = mask + b * SS;
  const int base = tid * 8;
  int loc[8], s = 0;
#pragma unroll
  for (int j = 0; j < 8; ++j) {
    loc[j] = m[base + j] != 0;
    s += loc[j];
  }
  part[tid] = s;
  __syncthreads();
  if (tid == 0) {
    int run = 0;
    for (int i = 0; i < 256; ++i) {
      int v = part[i];
      part[i] = run;
      run += v;
    }
    Sv[b] = run;
  }
  __syncthreads();
  int off = part[tid];
  int* ib = inv + b * SS;
#pragma unroll
  for (int j = 0; j < 8; ++j)
    if (loc[j]) ib[off++] = base + j;
}

// XCD-co-designed tile map: 512 tiles (64 m x 8 n), 8 XCDs.
static __device__ __forceinline__ void tile_map(int L, int& m0, int& n0) {
  const int xcd = L & 7, idx = L >> 3;
  m0 = (xcd * 8 + (idx >> 3)) * 128;
  n0 = (idx & 7) * 128;
}

// LDS chunk swizzle for 64B-row bf16 tiles: physical 16B-chunk =
// logical ^ ((row>>1)&3). Involution: same XOR on both sides.

// ------------- fused Q/K/V projection GEMMs, BOTH operands f32-reg-staged -
// A = q/k/v f32 (z>0: gathered valid rows); B = Wq/Wk/Wv f32 DIRECT from
// d_in. Both staged f32->reg, cvtpk->bf16 (RNE == f2bf bitwise), ds_write
// into the verified swizzled layout. 2 LDS buffers each; sync is
// lgkmcnt(0)+barrier only — all global loads are compiler-tracked reg loads.
// z=0: ->Qh [b,h,s,dk] *QK_SCALE; z=1: ->Kc compact; z=2: ->Vc transposed.
__global__ __launch_bounds__(256, 3) void gemm_qkv(const float* __restrict__ Aq,
                                                   const float* __restrict__ Ak,
                                                   const float* __restrict__ Av,
                                                   const float* __restrict__ Wq,
                                                   const float* __restrict__ Wk,
                                                   const float* __restrict__ Wv,
                                                   const int* __restrict__ inv,
                                                   const int* __restrict__ SvA,
                                                   u16* __restrict__ Qh,
                                                   u16* __restrict__ Kc,
                                                   u16* __restrict__ Vc) {
  __shared__ __align__(16) u16 Aw[2][128 * 32];   // bf16 A tiles (swizzled)
  __shared__ __align__(16) u16 Bw[2][128 * 32];   // bf16 B tiles (swizzled)
  const int z = blockIdx.z;
  const float* A = z == 0 ? Aq : z == 1 ? Ak : Av;
  const float* Bt = z == 0 ? Wq : z == 1 ? Wk : Wv;
  const int tid = threadIdx.x;
  const int l = tid & 63, w = tid >> 6;
  int m0, n0;
  tile_map((int)blockIdx.x, m0, n0);
  const int wr = w >> 1, wc = w & 1;
  const int lq = l & 15, hi = l >> 4;

  const int row_t = tid >> 2;        // + c*64
  const int col8 = (tid & 3) * 8;                      // logical fetch col
  const int swz_t = ((tid & 3) ^ ((row_t >> 1) & 3));  // staging chunk swizzle
  const int rslot = hi ^ ((lq >> 1) & 3);              // read-side chunk

  // A source-row resolution (K-loop invariant). z>0: gather via inv[].
  const float* rowp[2];
  {
    const int bb = m0 >> 11;
    if (z > 0) {
      const int svb = SvA[bb];
      const int lim64 = ((svb + 63) >> 6) << 6;
      if ((m0 & 2047) >= lim64) return;  // tile fully in dead zone
#pragma unroll
      for (int c = 0; c < 2; ++c) {
        int i = (m0 & 2047) + c * 64 + row_t;
        int ic = i < svb ? i : (svb > 0 ? svb - 1 : 0);
        rowp[c] = A + (size_t)(bb * SS + inv[bb * SS + ic]) * 1024 + col8;
      }
    } else {
#pragma unroll
      for (int c = 0; c < 2; ++c)
        rowp[c] = A + (size_t)(m0 + c * 64 + row_t) * 1024 + col8;
    }
  }
  const float* rowb[2];
#pragma unroll
  for (int c = 0; c < 2; ++c)
    rowb[c] = Bt + (size_t)(n0 + c * 64 + row_t) * 1024 + col8;

  f32x4 acc[4][4] = {};
  float4 rA0[2][2], rA1[2][2];   // A stage slots [c][half]
  float4 rB0[2][2], rB1[2][2];   // B stage slots [c][half]

#define ISSUE(RA, RB, kt)                                                      \
  do {                                                                         \
    _Pragma("unroll")                                                          \
    for (int c = 0; c < 2; ++c) {                                              \
      const float* ga = rowp[c] + (size_t)(kt) * 32;                           \
      RA[c][0] = *(const float4*)ga;                                           \
      RA[c][1] = *(const float4*)(ga + 4);                                     \
      const float* gb = rowb[c] + (size_t)(kt) * 32;                           \
      RB[c][0] = *(const float4*)gb;                                           \
      RB[c][1] = *(const float4*)(gb + 4);                                     \
    }                                                                          \
  } while (0)

#define DSWRITE(buf, RA, RB)                                                   \
  do {                                                                         \
    _Pragma("unroll")                                                          \
    for (int c = 0; c < 2; ++c) {                                              \
      uint4 pa;                                                                \
      pa.x = cvtpk(RA[c][0].x, RA[c][0].y);                                    \
      pa.y = cvtpk(RA[c][0].z, RA[c][0].w);                                    \
      pa.z = cvtpk(RA[c][1].x, RA[c][1].y);                                    \
      pa.w = cvtpk(RA[c][1].z, RA[c][1].w);                                    \
      *(uint4*)&Aw[buf][(c * 64 + row_t) * 32 + swz_t * 8] = pa;               \
      uint4 pb;                                                                \
      pb.x = cvtpk(RB[c][0].x, RB[c][0].y);                                    \
      pb.y = cvtpk(RB[c][0].z, RB[c][0].w);                                    \
      pb.z = cvtpk(RB[c][1].x, RB[c][1].y);                                    \
      pb.w = cvtpk(RB[c][1].z, RB[c][1].w);                                    \
      *(uint4*)&Bw[buf][(c * 64 + row_t) * 32 + swz_t * 8] = pb;               \
    }                                                                          \
  } while (0)

  auto compute = [&](int buf) {
    short8 af[4], bf[4];
#pragma unroll
    for (int i = 0; i < 4; ++i) {
      af[i] = *(const short8*)&Aw[buf][(wr * 64 + i * 16 + lq) * 32 + rslot * 8];
      bf[i] = *(const short8*)&Bw[buf][(wc * 64 + i * 16 + lq) * 32 + rslot * 8];
    }
#pragma unroll
    for (int i = 0; i < 4; ++i)
#pragma unroll
      for (int j = 0; j < 4; ++j) acc[i][j] = mfma16(af[i], bf[j], acc[i][j]);
  };

  // prologue: stages 0 and 1
  ISSUE(rA0, rB0, 0);
  ISSUE(rA1, rB1, 1);
  DSWRITE(0, rA0, rB0);  // compiler waits stage-0 loads here
  WAITLGKM0;
  __builtin_amdgcn_s_barrier();

  for (int kt = 0; kt < 30; kt += 2) {
    // even: compute stage kt (buf0); stage kt+2 -> slot0
    ISSUE(rA0, rB0, kt + 2);
    DSWRITE(1, rA1, rB1);   // stage kt+1 -> buf1 (read-done via prev barrier)
    compute(0);
    WAITLGKM0;
    __builtin_amdgcn_s_barrier();
    // odd: compute stage kt+1 (buf1); stage kt+3 -> slot1
    ISSUE(rA1, rB1, kt + 3);
    DSWRITE(0, rA0, rB0);   // stage kt+2 -> buf0
    compute(1);
    WAITLGKM0;
    __builtin_amdgcn_s_barrier();
  }
  // stages 30 (buf0, written in kt=28 odd) and 31 (in rA1/rB1)
  DSWRITE(1, rA1, rB1);     // stage 31 -> buf1
  compute(0);               // stage 30
  WAITLGKM0;
  __builtin_amdgcn_s_barrier();
  compute(1);               // stage 31

  const float oscale = z == 0 ? QK_SCALE : 1.0f;
#pragma unroll
  for (int i = 0; i < 4; ++i) {
#pragma unroll
    for (int j = 0; j < 4; ++j) {
      const int mg = m0 + wr * 64 + i * 16 + hi * 4;  // + r
      const int ng = n0 + wc * 64 + j * 16 + lq;
      const int h = ng >> 6, dk = ng & 63;
      if (z < 2) {
        u16* o = z == 0 ? Qh : Kc;
#pragma unroll
        for (int r = 0; r < 4; ++r) {
          int m = mg + r;
          int b = m >> 11, s = m & 2047;  // s == compact index for z=1
          o[(((size_t)(b * NHEADS + h) * SS + s) << 6) + dk] = f2bf(acc[i][j][r] * oscale);
        }
      } else {
        const int b = mg >> 11, s = mg & 2047;  // compact index, mult of 4
        uint2 pk;
        pk.x = (u32)f2bf(acc[i][j][0]) | ((u32)f2bf(acc[i][j][1]) << 16);
        pk.y = (u32)f2bf(acc[i][j][2]) | ((u32)f2bf(acc[i][j][3]) << 16);
        *(uint2*)&Vc[(((size_t)(b * NHEADS + h) * DK + dk) << 11) + s] = pk;
      }
    }
  }
#undef ISSUE
#undef DSWRITE
}

// ---------------- output GEMM: f32 out, swizzled LDS (verified) ----------
__global__ __launch_bounds__(256, 3) void gemm_out(const u16* __restrict__ A,
                                                   const u16* __restrict__ Bt,
                                                   float* __restrict__ out) {
  __shared__ __align__(16) u16 As[3][128 * 32];
  __shared__ __align__(16) u16 Bs[3][128 * 32];
  const int tid = threadIdx.x;
  const int l = tid & 63, w = tid >> 6;
  int m0, n0;
  tile_map((int)blockIdx.x, m0, n0);
  const int wr = w >> 1, wc = w & 1;
  const int lq = l & 15, hi = l >> 4;

  f32x4 acc[4][4] = {};

  const int row_t = tid >> 2;
  const int col8B = ((tid & 3) ^ ((row_t >> 1) & 3)) * 8;  // pre-swizzled src
  const int rslot = hi ^ ((lq >> 1) & 3);                  // read-side chunk

#define GSTAGE(buf, kt)                                                        \
  do {                                                                         \
    _Pragma("unroll")                                                          \
    for (int c = 0; c < 2; ++c) {                                              \
      int row = c * 64 + row_t;                                                \
      const u16* ga = A + (size_t)(m0 + row) * 1024 + (kt) * 32 + col8B;       \
      const u16* gb = Bt + (size_t)(n0 + row) * 1024 + (kt) * 32 + col8B;      \
      __builtin_amdgcn_global_load_lds(                                        \
          (const __attribute__((address_space(1))) void*)ga,                   \
          (__attribute__((address_space(3))) void*)&As[buf][(c * 256 + w * 64) * 8], \
          16, 0, 0);                                                           \
      __builtin_amdgcn_global_load_lds(                                        \
          (const __attribute__((address_space(1))) void*)gb,                   \
          (__attribute__((address_space(3))) void*)&Bs[buf][(c * 256 + w * 64) * 8], \
          16, 0, 0);                                                           \
    }                                                                          \
  } while (0)

  auto compute = [&](int kbuf) {
    short8 af[4], bf[4];
#pragma unroll
    for (int i = 0; i < 4; ++i) {
      af[i] = *(const short8*)&As[kbuf][(wr * 64 + i * 16 + lq) * 32 + rslot * 8];
      bf[i] = *(const short8*)&Bs[kbuf][(wc * 64 + i * 16 + lq) * 32 + rslot * 8];
    }
#pragma unroll
    for (int i = 0; i < 4; ++i)
#pragma unroll
      for (int j = 0; j < 4; ++j) acc[i][j] = mfma16(af[i], bf[j], acc[i][j]);
  };

  GSTAGE(0, 0);
  GSTAGE(1, 1);
  for (int kt = 0; kt < 31; ++kt) {
    WAITV4;
    __builtin_amdgcn_s_barrier();
    if (kt < 30) GSTAGE((kt + 2) % 3, kt + 2);
    compute(kt % 3);
  }
  WAITV0;
  __builtin_amdgcn_s_barrier();
  compute(31 % 3);

#pragma unroll
  for (int i = 0; i < 4; ++i)
#pragma unroll
    for (int j = 0; j < 4; ++j) {
      const int mg = m0 + wr * 64 + i * 16 + hi * 4;
      const int ng = n0 + wc * 64 + j * 16 + lq;
#pragma unroll
      for (int r = 0; r < 4; ++r) out[(size_t)(mg + r) * 1024 + ng] = acc[i][j][r];
    }
#undef GSTAGE
}

// ------- flash attention over COMPACTED K/V (R20/R21 verbatim) ------------
__global__ __launch_bounds__(256, 2) void attn_kernel(const u16* __restrict__ Qh,
                                                      const u16* __restrict__ Kc,
                                                      const u16* __restrict__ Vc,
                                                      const int* __restrict__ SvA,
                                                      u16* __restrict__ attn_out) {
  __shared__ __align__(16) u16 Ks[3][64 * 64];
  __shared__ __align__(16) u16 Vs[3][64 * 64];
  __shared__ __align__(16) float bias2[SS];
  const int tid = threadIdx.x;
  const int l = tid & 63, w = tid >> 6;  // w in 0..3
  int wg = ((int)blockIdx.x & 7) * 64 + ((int)blockIdx.x >> 3);
  const int qt = wg & 7, h = (wg >> 3) & 15, b = wg >> 7;
  const int lq = l & 15, hi = l >> 4;

  const int sv = SvA[b];
  const int NT = (sv + 63) >> 6;  // >=1 for this data
  for (int i = tid; i < SS; i += 256) bias2[i] = (i < sv) ? 0.0f : -1e13f;

  const size_t bh = (size_t)(b * NHEADS + h);
  const u16* Qp = Qh + bh * ((size_t)SS * DK);
  const u16* Kp = Kc + bh * ((size_t)SS * DK);
  const u16* Vp = Vc + bh * ((size_t)DK * SS);

  const int srow = tid >> 3;
  const int gchunk = (tid & 7) ^ (srow & 7);
  const u16* kg = Kp + (size_t)srow * 64 + gchunk * 8;          // + kv0*64
  const u16* vg = Vp + (size_t)srow * 2048 + gchunk * 8;        // + kv0
  const int ldsbase = w * 512;  // 8 rows * 64 elements per wave (inst0)

#define STAGE(buf, kv0)                                                         \
  do {                                                                          \
    __builtin_amdgcn_global_load_lds(                                           \
        (const __attribute__((address_space(1))) void*)(kg + (size_t)(kv0)*64), \
        (__attribute__((address_space(3))) void*)&Ks[buf][ldsbase], 16, 0, 0);  \
    __builtin_amdgcn_global_load_lds(                                           \
        (const __attribute__((address_space(1))) void*)(kg + (size_t)(kv0)*64 + \
                                                        32 * 64),               \
        (__attribute__((address_space(3))) void*)&Ks[buf][2048 + ldsbase], 16,  \
        0, 0);                                                                  \
    __builtin_amdgcn_global_load_lds(                                           \
        (const __attribute__((address_space(1))) void*)(vg + (kv0)),            \
        (__attribute__((address_space(3))) void*)&Vs[buf][ldsbase], 16, 0, 0);  \
    __builtin_amdgcn_global_load_lds(                                           \
        (const __attribute__((address_space(1))) void*)(vg + (kv0) + 32 * 2048),\
        (__attribute__((address_space(3))) void*)&Vs[buf][2048 + ldsbase], 16,  \
        0, 0);                                                                  \
  } while (0)

  const int q0 = qt * 256 + w * 64;
  short8 qf[4][2];
#pragma unroll
  for (int qg = 0; qg < 4; ++qg)
#pragma unroll
    for (int kd = 0; kd < 2; ++kd)
      qf[qg][kd] = *(const short8*)&Qp[(q0 + qg * 16 + lq) * 64 + kd * 32 + hi * 8];

  const short8 ones8 = {(short)0x3F80, (short)0x3F80, (short)0x3F80, (short)0x3F80,
                        (short)0x3F80, (short)0x3F80, (short)0x3F80, (short)0x3F80};

  f32x4 oacc[4][4] = {};
  f32x4 lacc[4] = {};
  const int rx = lq & 7;
  const int csw = ((hi ^ rx) * 8);  // swizzled chunk -> element offset

  auto computeAttn = [&](int it) {
    const int kv0 = it * 64;
    const int kbuf = it % 3;
    f32x4 st[4][4];
    __builtin_amdgcn_s_setprio(1);
#pragma unroll
    for (int t = 0; t < 4; ++t) {
      const u16* kp = &Ks[kbuf][(t * 16 + lq) * 64 + csw];
      short8 kf0 = *(const short8*)kp;
      short8 kf1 = *(const short8*)((uintptr_t)kp ^ 64);  // chunk ^4
      f32x4 bz = *(const f32x4*)&bias2[kv0 + t * 16 + hi * 4];
#pragma unroll
      for (int qg = 0; qg < 4; ++qg) {
        f32x4 zz = mfma16(kf0, qf[qg][0], bz);
        st[qg][t] = mfma16(kf1, qf[qg][1], zz);
      }
    }
    __builtin_amdgcn_s_setprio(0);

    short8 pfA[4], pfB[4];
#pragma unroll
    for (int qg = 0; qg < 4; ++qg) {
      u32 wd[4];
#pragma unroll
      for (int t2 = 0; t2 < 2; ++t2)
#pragma unroll
        for (int p = 0; p < 2; ++p)
          wd[t2 * 2 + p] = cvtpk(__builtin_amdgcn_exp2f(st[qg][t2][2 * p]),
                                 __builtin_amdgcn_exp2f(st[qg][t2][2 * p + 1]));
      u32 xd[4];
#pragma unroll
      for (int t2 = 0; t2 < 2; ++t2)
#pragma unroll
        for (int p = 0; p < 2; ++p)
          xd[t2 * 2 + p] = cvtpk(__builtin_amdgcn_exp2f(st[qg][2 + t2][2 * p]),
                                 __builtin_amdgcn_exp2f(st[qg][2 + t2][2 * p + 1]));
      pl32swap(wd[0], wd[2]);
      pl32swap(wd[1], wd[3]);
      pl16swap(wd[0], wd[2]);
      pl16swap(wd[1], wd[3]);
      uint4 pk = {wd[0], wd[1], wd[2], wd[3]};
      pfA[qg] = __builtin_bit_cast(short8, pk);
      pl32swap(xd[0], xd[2]);
      pl32swap(xd[1], xd[3]);
      pl16swap(xd[0], xd[2]);
      pl16swap(xd[1], xd[3]);
      uint4 pk2 = {xd[0], xd[1], xd[2], xd[3]};
      pfB[qg] = __builtin_bit_cast(short8, pk2);
    }

    __builtin_amdgcn_s_setprio(1);
#pragma unroll
    for (int dt = 0; dt < 4; ++dt) {
      const u16* vp = &Vs[kbuf][(dt * 16 + lq) * 64 + csw];
      short8 vf0 = *(const short8*)vp;
      short8 vf1 = *(const short8*)((uintptr_t)vp ^ 64);
#pragma unroll
      for (int qg = 0; qg < 4; ++qg) {
        oacc[qg][dt] = mfma16(vf0, pfA[qg], oacc[qg][dt]);
        oacc[qg][dt] = mfma16(vf1, pfB[qg], oacc[qg][dt]);
      }
    }
#pragma unroll
    for (int qg = 0; qg < 4; ++qg) {
      lacc[qg] = mfma16(ones8, pfA[qg], lacc[qg]);
      lacc[qg] = mfma16(ones8, pfB[qg], lacc[qg]);
    }
    __builtin_amdgcn_s_setprio(0);
  };

  STAGE(0, 0);
  if (NT > 1) STAGE(1, 64);
  __syncthreads();  // one-time full drain: bias2 ds_writes + S0/S1

  for (int it = 0; it < NT - 1; ++it) {
    WAITV4;                             // S(it) landed (S(it+1) may fly)
    __builtin_amdgcn_s_barrier();       // all waves done reading buf[(it-1)%3]
    if (it < NT - 2) STAGE((it + 2) % 3, (it + 2) * 64);
    computeAttn(it);
  }
  WAITV0;
  __builtin_amdgcn_s_barrier();
  computeAttn(NT - 1);

#pragma unroll
  for (int qg = 0; qg < 4; ++qg) {
    const float inv2 = 1.0f / lacc[qg][0];  // all regs equal = lsum(q)
    const int q = q0 + qg * 16 + lq;
    const size_t obase = (((size_t)(b * SS + q)) << 10) + h * 64;
#pragma unroll
    for (int dt = 0; dt < 4; ++dt) {
      const int dbase = dt * 16 + hi * 4;
      uint2 pk;
      pk.x = (u32)f2bf(oacc[qg][dt][0] * inv2) | ((u32)f2bf(oacc[qg][dt][1] * inv2) << 16);
      pk.y = (u32)f2bf(oacc[qg][dt][2] * inv2) | ((u32)f2bf(oacc[qg][dt][3] * inv2) << 16);
      *(uint2*)&attn_out[obase + dbase] = pk;
    }
  }
#undef STAGE
}

extern "C" void kernel_launch(void* const* d_in, const int* in_sizes, int n_in,
                              void* d_out, int out_size, void* d_ws, size_t ws_size,
                              hipStream_t stream) {
  const float* q_in = (const float*)d_in[0];
  const float* k_in = (const float*)d_in[1];
  const float* v_in = (const float*)d_in[2];
  const int* mask = (const int*)d_in[3];
  const float* Wq = (const float*)d_in[4];
  const float* Wk = (const float*)d_in[5];
  const float* Wv = (const float*)d_in[6];
  const float* Wo = (const float*)d_in[7];

  char* ws = (char*)d_ws;
  const size_t MB = 1ull << 20;
  u16* Kc  = (u16*)(ws + 0 * MB);    // 16MB compacted K
  u16* Vc  = (u16*)(ws + 16 * MB);   // 16MB compacted V^T
  int* inv = (int*)(ws + 32 * MB);   // 32KB
  int* Sv  = (int*)(ws + 33 * MB);   // 16B
  u16* wob = (u16*)(ws + 54 * MB);
  u16* Qh  = (u16*)(ws + 56 * MB);
  u16* attn = (u16*)(ws + 104 * MB);  // total 120MB

  const int NW4 = (D_MODEL * D_MODEL) / 4;
  scan_kernel<<<BB, 256, 0, stream>>>(mask, inv, Sv);
  cvt1_kernel<<<512, 256, 0, stream>>>(Wo, wob, NW4);

  gemm_qkv<<<dim3(512, 1, 3), 256, 0, stream>>>(
      q_in, k_in, v_in, Wq, Wk, Wv, inv, Sv, Qh, Kc, Vc);

  attn_kernel<<<512, 256, 0, stream>>>(Qh, Kc, Vc, Sv, attn);

  gemm_out<<<512, 256, 0, stream>>>(attn, wob, (float*)d_out);
}

// Round 23
// 159.465 us; speedup vs baseline: 1.0722x; 1.0722x over previous
//
#include <hip/hip_runtime.h>
#include <hip/hip_bf16.h>
#include <stdint.h>

typedef unsigned short u16;
typedef unsigned int u32;

#define D_MODEL 1024
#define NHEADS 16
#define DK 64
#define BB 4
#define SS 2048
#define M_TOT (BB * SS)  // 8192
#define QK_SCALE 0.18033688011112042f  // 0.125 * log2(e)

typedef __attribute__((ext_vector_type(8))) short short8;
typedef __attribute__((ext_vector_type(8))) __bf16 bf16x8;
typedef __attribute__((ext_vector_type(4))) float f32x4;

static __device__ __forceinline__ f32x4 mfma16(short8 a, short8 b, f32x4 c) {
  return __builtin_amdgcn_mfma_f32_16x16x32_bf16(
      __builtin_bit_cast(bf16x8, a), __builtin_bit_cast(bf16x8, b), c, 0, 0, 0);
}

// round-to-nearest-even f32 -> bf16
static __device__ __forceinline__ u16 f2bf(float f) {
  u32 u = __builtin_bit_cast(u32, f);
  u += 0x7fffu + ((u >> 16) & 1u);
  return (u16)(u >> 16);
}

// packed f32x2 -> bf16x2 (RNE); dst.lo = lo, dst.hi = hi
static __device__ __forceinline__ u32 cvtpk(float lo, float hi) {
  u32 r;
  asm("v_cvt_pk_bf16_f32 %0, %1, %2" : "=v"(r) : "v"(lo), "v"(hi));
  return r;
}
// swap a.lanes[32:63] <-> b.lanes[0:31]   (vdst.hi32 <-> vsrc.lo32)
static __device__ __forceinline__ void pl32swap(u32& a, u32& b) {
  asm("v_permlane32_swap_b32 %0, %1" : "+v"(a), "+v"(b));
}
// swap a.odd-16-rows <-> b.even-16-rows
static __device__ __forceinline__ void pl16swap(u32& a, u32& b) {
  asm("v_permlane16_swap_b32 %0, %1" : "+v"(a), "+v"(b));
}

// counted waits: loads stay in flight across barriers (T4)
#define WAITV6 asm volatile("s_waitcnt vmcnt(6)" ::: "memory")
#define WAITV4 asm volatile("s_waitcnt vmcnt(4)" ::: "memory")
#define WAITV0 asm volatile("s_waitcnt vmcnt(0)" ::: "memory")
#define WAITLGKM0 asm volatile("s_waitcnt lgkmcnt(0)" ::: "memory")

// ---------------- f32 -> bf16 convert (weights only) ----------------
__global__ void cvt4_kernel(const float* __restrict__ s0, const float* __restrict__ s1,
                            const float* __restrict__ s2, const float* __restrict__ s3,
                            u16* __restrict__ d0, u16* __restrict__ d1,
                            u16* __restrict__ d2, u16* __restrict__ d3, int n4) {
  const float* s = blockIdx.y == 0 ? s0 : blockIdx.y == 1 ? s1 : blockIdx.y == 2 ? s2 : s3;
  u16* d = blockIdx.y == 0 ? d0 : blockIdx.y == 1 ? d1 : blockIdx.y == 2 ? d2 : d3;
  int stride = gridDim.x * blockDim.x;
  for (int i = blockIdx.x * blockDim.x + threadIdx.x; i < n4; i += stride) {
    float4 v = reinterpret_cast<const float4*>(s)[i];
    ushort4 o;
    o.x = f2bf(v.x); o.y = f2bf(v.y); o.z = f2bf(v.z); o.w = f2bf(v.w);
    reinterpret_cast<ushort4*>(d)[i] = o;
  }
}

// ---------- mask prefix scan: inv[b][i] = i-th valid kv pos; Sv[b] --------
__global__ void scan_kernel(const int* __restrict__ mask, int* __restrict__ inv,
                            int* __restrict__ Sv) {
  __shared__ int part[256];
  const int b = blockIdx.x, tid = threadIdx.x;
  const int* m = mask + b * SS;
  const int base = tid * 8;
  int loc[8], s = 0;
#pragma unroll
  for (int j = 0; j < 8; ++j) {
    loc[j] = m[base + j] != 0;
    s += loc[j];
  }
  part[tid] = s;
  __syncthreads();
  if (tid == 0) {
    int run = 0;
    for (int i = 0; i < 256; ++i) {
      int v = part[i];
      part[i] = run;
      run += v;
    }
    Sv[b] = run;
  }
  __syncthreads();
  int off = part[tid];
  int* ib = inv + b * SS;
#pragma unroll
  for (int j = 0; j < 8; ++j)
    if (loc[j]) ib[off++] = base + j;
}

// XCD-co-designed tile map: 512 tiles (64 m x 8 n), 8 XCDs.
static __device__ __forceinline__ void tile_map(int L, int& m0, int& n0) {
  const int xcd = L & 7, idx = L >> 3;
  m0 = (xcd * 8 + (idx >> 3)) * 128;
  n0 = (idx & 7) * 128;
}

// LDS chunk swizzle for 64B-row bf16 tiles: physical 16B-chunk =
// logical ^ ((row>>1)&3). Involution: same XOR on both sides.

// ------------- fused Q/K/V projection GEMMs, f32 A reg-staged ------------
// z=0: full Q -> Qh [b,h,s,dk] (*QK_SCALE).
// z=1: K over GATHERED valid rows only -> Kc [b,h,i,dk] (compact; pad rows
//      are duplicated-last-valid -> killed by attn bias).
// z=2: V over gathered rows -> Vc [b,h,dk,i] (transposed compact; pad
//      columns killed by P=0).
// Tiles entirely past ceil(Sv/64)*64 early-exit (static grid, dynamic Sv).
__global__ __launch_bounds__(256, 3) void gemm_qkv(const float* __restrict__ Aq,
                                                   const float* __restrict__ Ak,
                                                   const float* __restrict__ Av,
                                                   const u16* __restrict__ wqb,
                                                   const u16* __restrict__ wkb,
                                                   const u16* __restrict__ wvb,
                                                   const int* __restrict__ inv,
                                                   const int* __restrict__ SvA,
                                                   u16* __restrict__ Qh,
                                                   u16* __restrict__ Kc,
                                                   u16* __restrict__ Vc) {
  __shared__ __align__(16) u16 Aw[2][128 * 32];   // bf16 A tiles (swizzled)
  __shared__ __align__(16) u16 Bs[3][128 * 32];   // bf16 B tiles (swizzled)
  const int z = blockIdx.z;
  const float* A = z == 0 ? Aq : z == 1 ? Ak : Av;
  const u16* Bt = z == 0 ? wqb : z == 1 ? wkb : wvb;
  const int tid = threadIdx.x;
  const int l = tid & 63, w = tid >> 6;
  int m0, n0;
  tile_map((int)blockIdx.x, m0, n0);
  const int wr = w >> 1, wc = w & 1;
  const int lq = l & 15, hi = l >> 4;

  const int row_t = tid >> 2;        // + c*64
  const int col8 = (tid & 3) * 8;                      // A logical fetch
  const int swz_t = ((tid & 3) ^ ((row_t >> 1) & 3));  // staging chunk swizzle
  const int col8B = swz_t * 8;                         // B pre-swizzled fetch
  const int rslot = hi ^ ((lq >> 1) & 3);              // read-side chunk

  // A source-row resolution (K-loop invariant). z>0: gather via inv[].
  const float* rowp[2];
  {
    const int bb = m0 >> 11;
    if (z > 0) {
      const int svb = SvA[bb];
      const int lim64 = ((svb + 63) >> 6) << 6;
      if ((m0 & 2047) >= lim64) return;  // tile fully in dead zone
#pragma unroll
      for (int c = 0; c < 2; ++c) {
        int i = (m0 & 2047) + c * 64 + row_t;
        int ic = i < svb ? i : (svb > 0 ? svb - 1 : 0);
        rowp[c] = A + (size_t)(bb * SS + inv[bb * SS + ic]) * 1024 + col8;
      }
    } else {
#pragma unroll
      for (int c = 0; c < 2; ++c)
        rowp[c] = A + (size_t)(m0 + c * 64 + row_t) * 1024 + col8;
    }
  }

  f32x4 acc[4][4] = {};
  float4 rA0[2][2], rA1[2][2];       // two register stage slots: [c][half]

#define ISSUE_A(R, kt)                                                         \
  do {                                                                         \
    _Pragma("unroll")                                                          \
    for (int c = 0; c < 2; ++c) {                                              \
      const float* ga = rowp[c] + (size_t)(kt) * 32;                           \
      R[c][0] = *(const float4*)ga;                                            \
      R[c][1] = *(const float4*)(ga + 4);                                      \
    }                                                                          \
  } while (0)

#define ISSUE_B(buf, kt)                                                       \
  do {                                                                         \
    _Pragma("unroll")                                                          \
    for (int c = 0; c < 2; ++c) {                                              \
      const u16* gb = Bt + (size_t)(n0 + c * 64 + row_t) * 1024 +              \
                      (size_t)(kt) * 32 + col8B;                               \
      __builtin_amdgcn_global_load_lds(                                        \
          (const __attribute__((address_space(1))) void*)gb,                   \
          (__attribute__((address_space(3))) void*)                            \
              &Bs[buf][(c * 256 + w * 64) * 8],                                \
          16, 0, 0);                                                           \
    }                                                                          \
  } while (0)

#define DSWRITE(abuf, R)                                                       \
  do {                                                                         \
    _Pragma("unroll")                                                          \
    for (int c = 0; c < 2; ++c) {                                              \
      uint4 pk4;                                                               \
      pk4.x = cvtpk(R[c][0].x, R[c][0].y);                                     \
      pk4.y = cvtpk(R[c][0].z, R[c][0].w);                                     \
      pk4.z = cvtpk(R[c][1].x, R[c][1].y);                                     \
      pk4.w = cvtpk(R[c][1].z, R[c][1].w);                                     \
      *(uint4*)&Aw[abuf][(c * 64 + row_t) * 32 + swz_t * 8] = pk4;             \
    }                                                                          \
  } while (0)

  auto compute = [&](int abuf, int bbuf) {
    short8 af[4], bf[4];
#pragma unroll
    for (int i = 0; i < 4; ++i) {
      af[i] = *(const short8*)&Aw[abuf][(wr * 64 + i * 16 + lq) * 32 + rslot * 8];
      bf[i] = *(const short8*)&Bs[bbuf][(wc * 64 + i * 16 + lq) * 32 + rslot * 8];
    }
#pragma unroll
    for (int i = 0; i < 4; ++i)
#pragma unroll
      for (int j = 0; j < 4; ++j) acc[i][j] = mfma16(af[i], bf[j], acc[i][j]);
  };

  // prologue: stages 0 and 1
  ISSUE_A(rA0, 0);
  ISSUE_B(0, 0);
  ISSUE_A(rA1, 1);
  ISSUE_B(1, 1);
  DSWRITE(0, rA0);
  WAITV6;
  WAITLGKM0;
  __builtin_amdgcn_s_barrier();

  for (int kt = 0; kt < 30; kt += 2) {
    ISSUE_A(rA0, kt + 2);
    ISSUE_B((kt + 2) % 3, kt + 2);
    DSWRITE(1, rA1);
    compute(0, kt % 3);
    WAITV6;
    WAITLGKM0;
    __builtin_amdgcn_s_barrier();
    ISSUE_A(rA1, kt + 3);
    ISSUE_B((kt + 3) % 3, kt + 3);
    DSWRITE(0, rA0);
    compute(1, (kt + 1) % 3);
    WAITV6;
    WAITLGKM0;
    __builtin_amdgcn_s_barrier();
  }
  DSWRITE(1, rA1);
  compute(0, 30 % 3);
  WAITV0;
  WAITLGKM0;
  __builtin_amdgcn_s_barrier();
  compute(1, 31 % 3);

  const float oscale = z == 0 ? QK_SCALE : 1.0f;
#pragma unroll
  for (int i = 0; i < 4; ++i) {
#pragma unroll
    for (int j = 0; j < 4; ++j) {
      const int mg = m0 + wr * 64 + i * 16 + hi * 4;  // + r
      const int ng = n0 + wc * 64 + j * 16 + lq;
      const int h = ng >> 6, dk = ng & 63;
      if (z < 2) {
        u16* o = z == 0 ? Qh : Kc;
#pragma unroll
        for (int r = 0; r < 4; ++r) {
          int m = mg + r;
          int b = m >> 11, s = m & 2047;  // s == compact index for z=1
          o[(((size_t)(b * NHEADS + h) * SS + s) << 6) + dk] = f2bf(acc[i][j][r] * oscale);
        }
      } else {
        const int b = mg >> 11, s = mg & 2047;  // compact index, mult of 4
        uint2 pk;
        pk.x = (u32)f2bf(acc[i][j][0]) | ((u32)f2bf(acc[i][j][1]) << 16);
        pk.y = (u32)f2bf(acc[i][j][2]) | ((u32)f2bf(acc[i][j][3]) << 16);
        *(uint2*)&Vc[(((size_t)(b * NHEADS + h) * DK + dk) << 11) + s] = pk;
      }
    }
  }
#undef ISSUE_A
#undef ISSUE_B
#undef DSWRITE
}

// ---------------- output GEMM: f32 out, swizzled LDS ----------------
__global__ __launch_bounds__(256, 3) void gemm_out(const u16* __restrict__ A,
                                                   const u16* __restrict__ Bt,
                                                   float* __restrict__ out) {
  __shared__ __align__(16) u16 As[3][128 * 32];
  __shared__ __align__(16) u16 Bs[3][128 * 32];
  const int tid = threadIdx.x;
  const int l = tid & 63, w = tid >> 6;
  int m0, n0;
  tile_map((int)blockIdx.x, m0, n0);
  const int wr = w >> 1, wc = w & 1;
  const int lq = l & 15, hi = l >> 4;

  f32x4 acc[4][4] = {};

  const int row_t = tid >> 2;
  const int col8B = ((tid & 3) ^ ((row_t >> 1) & 3)) * 8;  // pre-swizzled src
  const int rslot = hi ^ ((lq >> 1) & 3);                  // read-side chunk

#define GSTAGE(buf, kt)                                                        \
  do {                                                                         \
    _Pragma("unroll")                                                          \
    for (int c = 0; c < 2; ++c) {                                              \
      int row = c * 64 + row_t;                                                \
      const u16* ga = A + (size_t)(m0 + row) * 1024 + (kt) * 32 + col8B;       \
      const u16* gb = Bt + (size_t)(n0 + row) * 1024 + (kt) * 32 + col8B;      \
      __builtin_amdgcn_global_load_lds(                                        \
          (const __attribute__((address_space(1))) void*)ga,                   \
          (__attribute__((address_space(3))) void*)&As[buf][(c * 256 + w * 64) * 8], \
          16, 0, 0);                                                           \
      __builtin_amdgcn_global_load_lds(                                        \
          (const __attribute__((address_space(1))) void*)gb,                   \
          (__attribute__((address_space(3))) void*)&Bs[buf][(c * 256 + w * 64) * 8], \
          16, 0, 0);                                                           \
    }                                                                          \
  } while (0)

  auto compute = [&](int kbuf) {
    short8 af[4], bf[4];
#pragma unroll
    for (int i = 0; i < 4; ++i) {
      af[i] = *(const short8*)&As[kbuf][(wr * 64 + i * 16 + lq) * 32 + rslot * 8];
      bf[i] = *(const short8*)&Bs[kbuf][(wc * 64 + i * 16 + lq) * 32 + rslot * 8];
    }
#pragma unroll
    for (int i = 0; i < 4; ++i)
#pragma unroll
      for (int j = 0; j < 4; ++j) acc[i][j] = mfma16(af[i], bf[j], acc[i][j]);
  };

  GSTAGE(0, 0);
  GSTAGE(1, 1);
  for (int kt = 0; kt < 31; ++kt) {
    WAITV4;
    __builtin_amdgcn_s_barrier();
    if (kt < 30) GSTAGE((kt + 2) % 3, kt + 2);
    compute(kt % 3);
  }
  WAITV0;
  __builtin_amdgcn_s_barrier();
  compute(31 % 3);

#pragma unroll
  for (int i = 0; i < 4; ++i)
#pragma unroll
    for (int j = 0; j < 4; ++j) {
      const int mg = m0 + wr * 64 + i * 16 + hi * 4;
      const int ng = n0 + wc * 64 + j * 16 + lq;
#pragma unroll
      for (int r = 0; r < 4; ++r) out[(size_t)(mg + r) * 1024 + ng] = acc[i][j][r];
    }
#undef GSTAGE
}

// ------- flash attention over COMPACTED K/V (verified R20/R21) ------------
__global__ __launch_bounds__(256, 2) void attn_kernel(const u16* __restrict__ Qh,
                                                      const u16* __restrict__ Kc,
                                                      const u16* __restrict__ Vc,
                                                      const int* __restrict__ SvA,
                                                      u16* __restrict__ attn_out) {
  __shared__ __align__(16) u16 Ks[3][64 * 64];
  __shared__ __align__(16) u16 Vs[3][64 * 64];
  __shared__ __align__(16) float bias2[SS];
  const int tid = threadIdx.x;
  const int l = tid & 63, w = tid >> 6;  // w in 0..3
  int wg = ((int)blockIdx.x & 7) * 64 + ((int)blockIdx.x >> 3);
  const int qt = wg & 7, h = (wg >> 3) & 15, b = wg >> 7;
  const int lq = l & 15, hi = l >> 4;

  const int sv = SvA[b];
  const int NT = (sv + 63) >> 6;  // >=1 for this data
  for (int i = tid; i < SS; i += 256) bias2[i] = (i < sv) ? 0.0f : -1e13f;

  const size_t bh = (size_t)(b * NHEADS + h);
  const u16* Qp = Qh + bh * ((size_t)SS * DK);
  const u16* Kp = Kc + bh * ((size_t)SS * DK);
  const u16* Vp = Vc + bh * ((size_t)DK * SS);

  const int srow = tid >> 3;
  const int gchunk = (tid & 7) ^ (srow & 7);
  const u16* kg = Kp + (size_t)srow * 64 + gchunk * 8;          // + kv0*64
  const u16* vg = Vp + (size_t)srow * 2048 + gchunk * 8;        // + kv0
  const int ldsbase = w * 512;  // 8 rows * 64 elements per wave (inst0)

#define STAGE(buf, kv0)                                                         \
  do {                                                                          \
    __builtin_amdgcn_global_load_lds(                                           \
        (const __attribute__((address_space(1))) void*)(kg + (size_t)(kv0)*64), \
        (__attribute__((address_space(3))) void*)&Ks[buf][ldsbase], 16, 0, 0);  \
    __builtin_amdgcn_global_load_lds(                                           \
        (const __attribute__((address_space(1))) void*)(kg + (size_t)(kv0)*64 + \
                                                        32 * 64),               \
        (__attribute__((address_space(3))) void*)&Ks[buf][2048 + ldsbase], 16,  \
        0, 0);                                                                  \
    __builtin_amdgcn_global_load_lds(                                           \
        (const __attribute__((address_space(1))) void*)(vg + (kv0)),            \
        (__attribute__((address_space(3))) void*)&Vs[buf][ldsbase], 16, 0, 0);  \
    __builtin_amdgcn_global_load_lds(                                           \
        (const __attribute__((address_space(1))) void*)(vg + (kv0) + 32 * 2048),\
        (__attribute__((address_space(3))) void*)&Vs[buf][2048 + ldsbase], 16,  \
        0, 0);                                                                  \
  } while (0)

  const int q0 = qt * 256 + w * 64;
  short8 qf[4][2];
#pragma unroll
  for (int qg = 0; qg < 4; ++qg)
#pragma unroll
    for (int kd = 0; kd < 2; ++kd)
      qf[qg][kd] = *(const short8*)&Qp[(q0 + qg * 16 + lq) * 64 + kd * 32 + hi * 8];

  const short8 ones8 = {(short)0x3F80, (short)0x3F80, (short)0x3F80, (short)0x3F80,
                        (short)0x3F80, (short)0x3F80, (short)0x3F80, (short)0x3F80};

  f32x4 oacc[4][4] = {};
  f32x4 lacc[4] = {};
  const int rx = lq & 7;
  const int csw = ((hi ^ rx) * 8);  // swizzled chunk -> element offset

  auto computeAttn = [&](int it) {
    const int kv0 = it * 64;
    const int kbuf = it % 3;
    f32x4 st[4][4];
    __builtin_amdgcn_s_setprio(1);
#pragma unroll
    for (int t = 0; t < 4; ++t) {
      const u16* kp = &Ks[kbuf][(t * 16 + lq) * 64 + csw];
      short8 kf0 = *(const short8*)kp;
      short8 kf1 = *(const short8*)((uintptr_t)kp ^ 64);  // chunk ^4
      f32x4 bz = *(const f32x4*)&bias2[kv0 + t * 16 + hi * 4];
#pragma unroll
      for (int qg = 0; qg < 4; ++qg) {
        f32x4 zz = mfma16(kf0, qf[qg][0], bz);
        st[qg][t] = mfma16(kf1, qf[qg][1], zz);
      }
    }
    __builtin_amdgcn_s_setprio(0);

    short8 pfA[4], pfB[4];
#pragma unroll
    for (int qg = 0; qg < 4; ++qg) {
      u32 wd[4];
#pragma unroll
      for (int t2 = 0; t2 < 2; ++t2)
#pragma unroll
        for (int p = 0; p < 2; ++p)
          wd[t2 * 2 + p] = cvtpk(__builtin_amdgcn_exp2f(st[qg][t2][2 * p]),
                                 __builtin_amdgcn_exp2f(st[qg][t2][2 * p + 1]));
      u32 xd[4];
#pragma unroll
      for (int t2 = 0; t2 < 2; ++t2)
#pragma unroll
        for (int p = 0; p < 2; ++p)
          xd[t2 * 2 + p] = cvtpk(__builtin_amdgcn_exp2f(st[qg][2 + t2][2 * p]),
                                 __builtin_amdgcn_exp2f(st[qg][2 + t2][2 * p + 1]));
      pl32swap(wd[0], wd[2]);
      pl32swap(wd[1], wd[3]);
      pl16swap(wd[0], wd[2]);
      pl16swap(wd[1], wd[3]);
      uint4 pk = {wd[0], wd[1], wd[2], wd[3]};
      pfA[qg] = __builtin_bit_cast(short8, pk);
      pl32swap(xd[0], xd[2]);
      pl32swap(xd[1], xd[3]);
      pl16swap(xd[0], xd[2]);
      pl16swap(xd[1], xd[3]);
      uint4 pk2 = {xd[0], xd[1], xd[2], xd[3]};
      pfB[qg] = __builtin_bit_cast(short8, pk2);
    }

    __builtin_amdgcn_s_setprio(1);
#pragma unroll
    for (int dt = 0; dt < 4; ++dt) {
      const u16* vp = &Vs[kbuf][(dt * 16 + lq) * 64 + csw];
      short8 vf0 = *(const short8*)vp;
      short8 vf1 = *(const short8*)((uintptr_t)vp ^ 64);
#pragma unroll
      for (int qg = 0; qg < 4; ++qg) {
        oacc[qg][dt] = mfma16(vf0, pfA[qg], oacc[qg][dt]);
        oacc[qg][dt] = mfma16(vf1, pfB[qg], oacc[qg][dt]);
      }
    }
#pragma unroll
    for (int qg = 0; qg < 4; ++qg) {
      lacc[qg] = mfma16(ones8, pfA[qg], lacc[qg]);
      lacc[qg] = mfma16(ones8, pfB[qg], lacc[qg]);
    }
    __builtin_amdgcn_s_setprio(0);
  };

  STAGE(0, 0);
  if (NT > 1) STAGE(1, 64);
  __syncthreads();  // one-time full drain: bias2 ds_writes + S0/S1

  for (int it = 0; it < NT - 1; ++it) {
    WAITV4;                             // S(it) landed (S(it+1) may fly)
    __builtin_amdgcn_s_barrier();       // all waves done reading buf[(it-1)%3]
    if (it < NT - 2) STAGE((it + 2) % 3, (it + 2) * 64);
    computeAttn(it);
  }
  WAITV0;
  __builtin_amdgcn_s_barrier();
  computeAttn(NT - 1);

#pragma unroll
  for (int qg = 0; qg < 4; ++qg) {
    const float inv2 = 1.0f / lacc[qg][0];  // all regs equal = lsum(q)
    const int q = q0 + qg * 16 + lq;
    const size_t obase = (((size_t)(b * SS + q)) << 10) + h * 64;
#pragma unroll
    for (int dt = 0; dt < 4; ++dt) {
      const int dbase = dt * 16 + hi * 4;
      uint2 pk;
      pk.x = (u32)f2bf(oacc[qg][dt][0] * inv2) | ((u32)f2bf(oacc[qg][dt][1] * inv2) << 16);
      pk.y = (u32)f2bf(oacc[qg][dt][2] * inv2) | ((u32)f2bf(oacc[qg][dt][3] * inv2) << 16);
      *(uint2*)&attn_out[obase + dbase] = pk;
    }
  }
#undef STAGE
}

extern "C" void kernel_launch(void* const* d_in, const int* in_sizes, int n_in,
                              void* d_out, int out_size, void* d_ws, size_t ws_size,
                              hipStream_t stream) {
  const float* q_in = (const float*)d_in[0];
  const float* k_in = (const float*)d_in[1];
  const float* v_in = (const float*)d_in[2];
  const int* mask = (const int*)d_in[3];
  const float* Wq = (const float*)d_in[4];
  const float* Wk = (const float*)d_in[5];
  const float* Wv = (const float*)d_in[6];
  const float* Wo = (const float*)d_in[7];

  char* ws = (char*)d_ws;
  const size_t MB = 1ull << 20;
  u16* Kc  = (u16*)(ws + 0 * MB);    // 16MB compacted K
  u16* Vc  = (u16*)(ws + 16 * MB);   // 16MB compacted V^T
  int* inv = (int*)(ws + 32 * MB);   // 32KB
  int* Sv  = (int*)(ws + 33 * MB);   // 16B
  u16* wqb = (u16*)(ws + 48 * MB);
  u16* wkb = (u16*)(ws + 50 * MB);
  u16* wvb = (u16*)(ws + 52 * MB);
  u16* wob = (u16*)(ws + 54 * MB);
  u16* Qh  = (u16*)(ws + 56 * MB);
  u16* attn = (u16*)(ws + 104 * MB);  // total 120MB

  const int NW4 = (D_MODEL * D_MODEL) / 4;
  scan_kernel<<<BB, 256, 0, stream>>>(mask, inv, Sv);
  cvt4_kernel<<<dim3(512, 4), 256, 0, stream>>>(Wq, Wk, Wv, Wo,
                                                wqb, wkb, wvb, wob, NW4);

  gemm_qkv<<<dim3(512, 1, 3), 256, 0, stream>>>(
      q_in, k_in, v_in, wqb, wkb, wvb, inv, Sv, Qh, Kc, Vc);

  attn_kernel<<<512, 256, 0, stream>>>(Qh, Kc, Vc, Sv, attn);

  gemm_out<<<512, 256, 0, stream>>>(attn, wob, (float*)d_out);
}